// Round 6
// baseline (19933.171 us; speedup 1.0000x reference)
//
#include <hip/hip_runtime.h>
#include <math.h>

#define DINLINE __device__ __forceinline__

DINLINE float sigmoidf_(float x) { return 1.f / (1.f + expf(-x)); }

// All scratch in static device memory — independent of ws_size (verified graph-safe R3-R5).
__device__ __align__(256) float g_ws[36200000];

// ---------------- im2col for the two convs ----------------
__global__ void im2col1_kernel(const float* __restrict__ feat, float* __restrict__ P) {
  size_t i = (size_t)blockIdx.x * 256 + threadIdx.x;
  int col = (int)(i % 1280);
  int row = (int)(i / 1280);
  int c = col / 5, k = col - c * 5;
  int l = row & 255, b = row >> 8;
  int pos = 2 * l + k - 2;
  P[i] = (pos >= 0 && pos < 512) ? feat[((size_t)b * 512 + pos) * 256 + c] : 0.f;
}

__global__ void im2col2_kernel(const float* __restrict__ y1, float* __restrict__ P) {
  size_t i = (size_t)blockIdx.x * 256 + threadIdx.x;
  int col = (int)(i % 2560);
  int row = (int)(i / 2560);
  int c = col / 5, k = col - c * 5;
  int l = row & 127, b = row >> 7;
  int pos = 2 * l + k - 2;
  P[i] = (pos >= 0 && pos < 256) ? y1[((size_t)b * 256 + pos) * 512 + c] : 0.f;
}

// ---------------- fp32 tiled GEMM: C[m,n] = sum_k A[m,k]*B[n,k] + bias[n], opt relu ----
__global__ __launch_bounds__(256) void sgemm128(
    const float* __restrict__ A, const float* __restrict__ B,
    const float* __restrict__ bias, float* __restrict__ C,
    int M, int N, int K, int relu) {
  __shared__ float As[8][132];
  __shared__ float Bs[8][132];
  int bm = blockIdx.y * 128, bn = blockIdx.x * 128;
  int tid = threadIdx.x;
  int tx = tid & 15, ty = tid >> 4;
  float acc[8][8];
#pragma unroll
  for (int i = 0; i < 8; ++i)
#pragma unroll
    for (int j = 0; j < 8; ++j) acc[i][j] = 0.f;
  int lr = tid >> 1;
  int lc = (tid & 1) * 4;
  const float* Arow = A + (size_t)(bm + lr) * K + lc;
  const float* Brow = B + (size_t)(bn + lr) * K + lc;
  for (int k0 = 0; k0 < K; k0 += 8) {
    float4 av = *(const float4*)(Arow + k0);
    float4 bv = *(const float4*)(Brow + k0);
    As[lc + 0][lr] = av.x; As[lc + 1][lr] = av.y; As[lc + 2][lr] = av.z; As[lc + 3][lr] = av.w;
    Bs[lc + 0][lr] = bv.x; Bs[lc + 1][lr] = bv.y; Bs[lc + 2][lr] = bv.z; Bs[lc + 3][lr] = bv.w;
    __syncthreads();
#pragma unroll
    for (int kk = 0; kk < 8; ++kk) {
      float4 a0 = *(const float4*)&As[kk][ty * 8];
      float4 a1 = *(const float4*)&As[kk][ty * 8 + 4];
      float4 b0 = *(const float4*)&Bs[kk][tx * 8];
      float4 b1 = *(const float4*)&Bs[kk][tx * 8 + 4];
      float aa[8] = {a0.x, a0.y, a0.z, a0.w, a1.x, a1.y, a1.z, a1.w};
      float bb[8] = {b0.x, b0.y, b0.z, b0.w, b1.x, b1.y, b1.z, b1.w};
#pragma unroll
      for (int i = 0; i < 8; ++i)
#pragma unroll
        for (int j = 0; j < 8; ++j) acc[i][j] += aa[i] * bb[j];
    }
    __syncthreads();
  }
#pragma unroll
  for (int i = 0; i < 8; ++i) {
    int m = bm + ty * 8 + i;
#pragma unroll
    for (int j = 0; j < 8; ++j) {
      int n = bn + tx * 8 + j;
      float v = acc[i][j] + (bias ? bias[n] : 0.f);
      if (relu) v = fmaxf(v, 0.f);
      C[(size_t)m * N + n] = v;
    }
  }
}

// ---------------- fused bidirectional encoder GRU step ----------------
// 256 blocks x 128 thr (all CUs busy): dir = blk>>7, j = (blk&127)*4 + tid>>5, b = tid&31.
__global__ __launch_bounds__(128) void enc_gru_step(
    const float* __restrict__ gi_f, const float* __restrict__ gi_b,
    const float* __restrict__ Whh_f, const float* __restrict__ bhh_f,
    const float* __restrict__ Whh_b, const float* __restrict__ bhh_b,
    const float* __restrict__ h_in, float* __restrict__ h_out,
    float* __restrict__ enc_out, int s) {
  int dir = blockIdx.x >> 7;
  int j = ((blockIdx.x & 127) << 2) + (threadIdx.x >> 5);
  int b = threadIdx.x & 31;
  __shared__ float4 hs4[4096];
  const float4* hbase = (const float4*)(h_in + dir * 32 * 512);
  for (int i = threadIdx.x; i < 4096; i += 128) {
    int bb = i >> 7, kf = i & 127;
    hs4[(bb << 7) + (kf ^ (bb & 7))] = hbase[i];
  }
  __syncthreads();
  const float* gi = dir ? gi_b : gi_f;
  const float* Whh = dir ? Whh_b : Whh_f;
  const float* bhh = dir ? bhh_b : bhh_f;
  int t = dir ? (127 - s) : s;
  const float4* wr = (const float4*)(Whh + (size_t)j * 512);
  const float4* wz = (const float4*)(Whh + (size_t)(512 + j) * 512);
  const float4* wn = (const float4*)(Whh + (size_t)(1024 + j) * 512);
  const float4* hrow = hs4 + b * 128;
  int sw = b & 7;
  float sr = 0.f, sz = 0.f, sn = 0.f;
#pragma unroll 4
  for (int kf = 0; kf < 128; ++kf) {
    float4 hv = hrow[kf ^ sw];
    float4 r4 = wr[kf];
    float4 z4 = wz[kf];
    float4 n4 = wn[kf];
    sr += hv.x * r4.x + hv.y * r4.y + hv.z * r4.z + hv.w * r4.w;
    sz += hv.x * z4.x + hv.y * z4.y + hv.z * z4.z + hv.w * z4.w;
    sn += hv.x * n4.x + hv.y * n4.y + hv.z * n4.z + hv.w * n4.w;
  }
  const float* g = gi + ((size_t)b * 128 + t) * 1536;
  float r = sigmoidf_(g[j] + sr + bhh[j]);
  float z = sigmoidf_(g[512 + j] + sz + bhh[512 + j]);
  float n = tanhf(g[1024 + j] + r * (sn + bhh[1024 + j]));
  float4 hj4 = hrow[(j >> 2) ^ sw];
  float hj = ((const float*)&hj4)[j & 3];
  float hnew = (1.f - z) * n + z * hj;
  h_out[dir * 32 * 512 + b * 512 + j] = hnew;
  enc_out[((size_t)b * 128 + t) * 1024 + dir * 512 + j] = hnew;
}

// ---------------- fused decoder GRU: gi = X@Wih^T + bih inline + h@Whh^T + gates ----
// X[b,:] = concat(src1(b)[len1], src2(b)[len2]); src1 = tokidx ? A1[tok[b]] : A1[b].
// grid 64 x 256: b = tid&31, j = blk*8 + tid>>5. Phase A: X chunks (16KB LDS, XOR-swz
// kf^b vs 32-way bank conflict). Phase B: h staged 64KB (R4-proven kf^(b&7) swizzle).
// keys_zero: if non-null, block 0 zeroes the 32 argmax keys (ordering: runs before proj).
__global__ __launch_bounds__(256) void dec_gru_fused(
    const float* __restrict__ A1, const int* __restrict__ tokidx, int len1,
    const float* __restrict__ A2, int len2,
    const float* __restrict__ Wih, const float* __restrict__ bih,
    const float* __restrict__ Whh, const float* __restrict__ bhh,
    const float* __restrict__ h_in, float* __restrict__ h_out,
    unsigned long long* __restrict__ keys_zero) {
  __shared__ float4 buf[4096];  // 64KB, phased: X chunks then h
  int tid = threadIdx.x;
  int b = tid & 31, j = (blockIdx.x << 3) + (tid >> 5);
  if (keys_zero && blockIdx.x == 0 && tid < 32) keys_zero[tid] = 0ULL;
  int Kin = len1 + len2;
  const float4* wir = (const float4*)(Wih + (size_t)j * Kin);
  const float4* wiz = (const float4*)(Wih + (size_t)(512 + j) * Kin);
  const float4* win = (const float4*)(Wih + (size_t)(1024 + j) * Kin);
  int K4 = Kin >> 2, len1_4 = len1 >> 2;
  float gr = 0.f, gz = 0.f, gn = 0.f;
  int sw5 = b & 31;
  for (int k0 = 0; k0 < K4; k0 += 32) {
    __syncthreads();
    for (int idx = tid; idx < 1024; idx += 256) {
      int bb = idx >> 5, kf = idx & 31;
      int gk = k0 + kf;
      float4 v;
      if (gk < len1_4) {
        const float* src = tokidx ? (A1 + (size_t)tokidx[bb] * len1) : (A1 + (size_t)bb * len1);
        v = ((const float4*)src)[gk];
      } else {
        v = ((const float4*)(A2 + (size_t)bb * len2))[gk - len1_4];
      }
      buf[(bb << 5) + (kf ^ (bb & 31))] = v;
    }
    __syncthreads();
    const float4* xrow = buf + (b << 5);
    const float4* wr_ = wir + k0;
    const float4* wz_ = wiz + k0;
    const float4* wn_ = win + k0;
#pragma unroll 4
    for (int kf = 0; kf < 32; ++kf) {
      float4 xv = xrow[kf ^ sw5];
      float4 r4 = wr_[kf];
      float4 z4 = wz_[kf];
      float4 n4 = wn_[kf];
      gr += xv.x * r4.x + xv.y * r4.y + xv.z * r4.z + xv.w * r4.w;
      gz += xv.x * z4.x + xv.y * z4.y + xv.z * z4.z + xv.w * z4.w;
      gn += xv.x * n4.x + xv.y * n4.y + xv.z * n4.z + xv.w * n4.w;
    }
  }
  // Phase B: h @ Whh
  __syncthreads();
  const float4* hbase = (const float4*)h_in;
  for (int i = tid; i < 4096; i += 256) {
    int bb = i >> 7, kf = i & 127;
    buf[(bb << 7) + (kf ^ (bb & 7))] = hbase[i];
  }
  __syncthreads();
  const float4* whr = (const float4*)(Whh + (size_t)j * 512);
  const float4* whz = (const float4*)(Whh + (size_t)(512 + j) * 512);
  const float4* whn = (const float4*)(Whh + (size_t)(1024 + j) * 512);
  const float4* hrow = buf + (b << 7);
  int sw = b & 7;
  float sr = 0.f, sz = 0.f, sn = 0.f;
#pragma unroll 4
  for (int kf = 0; kf < 128; ++kf) {
    float4 hv = hrow[kf ^ sw];
    float4 r4 = whr[kf];
    float4 z4 = whz[kf];
    float4 n4 = whn[kf];
    sr += hv.x * r4.x + hv.y * r4.y + hv.z * r4.z + hv.w * r4.w;
    sz += hv.x * z4.x + hv.y * z4.y + hv.z * z4.z + hv.w * z4.w;
    sn += hv.x * n4.x + hv.y * n4.y + hv.z * n4.z + hv.w * n4.w;
  }
  float r = sigmoidf_(gr + bih[j] + sr + bhh[j]);
  float z = sigmoidf_(gz + bih[512 + j] + sz + bhh[512 + j]);
  float n = tanhf(gn + bih[1024 + j] + r * (sn + bhh[1024 + j]));
  float4 hj4 = hrow[(j >> 2) ^ sw];
  float hj = ((const float*)&hj4)[j & 3];
  h_out[b * 512 + j] = (1.f - z) * n + z * hj;
}

// ---------------- batch-shared GEMV (bridge only) ----------------
__global__ __launch_bounds__(256) void gemvB(
    const float* __restrict__ A1, const int* __restrict__ tokidx, int len1,
    const float* __restrict__ A2, int len2,
    const float* __restrict__ W, const float* __restrict__ bias,
    float* __restrict__ out0, float* __restrict__ out1, int split, int N, int K) {
  int tid = threadIdx.x;
  int s = tid & 7, nl = tid >> 3;
  int n = blockIdx.x * 32 + nl;
  __shared__ float4 xs4[32 * 32];
  float acc[32];
#pragma unroll
  for (int b = 0; b < 32; ++b) acc[b] = 0.f;
  const float4* W4 = (const float4*)(W + (size_t)n * K);
  int K4 = K >> 2;
  int len1_4 = len1 >> 2;
  for (int k0 = 0; k0 < K4; k0 += 32) {
    __syncthreads();
    for (int idx = tid; idx < 1024; idx += 256) {
      int b = idx >> 5, kf = idx & 31;
      int gk = k0 + kf;
      float4 v;
      if (gk < len1_4) {
        const float* src = tokidx ? (A1 + (size_t)tokidx[b] * len1) : (A1 + (size_t)b * len1);
        v = ((const float4*)src)[gk];
      } else {
        v = ((const float4*)(A2 + (size_t)b * len2))[gk - len1_4];
      }
      xs4[idx] = v;
    }
    __syncthreads();
    const float4* wp = W4 + k0;
#pragma unroll
    for (int j = 0; j < 4; ++j) {
      float4 wv = wp[j * 8 + s];
      const float4* xp = xs4 + j * 8 + s;
#pragma unroll
      for (int b = 0; b < 32; ++b) {
        float4 xv = xp[b * 32];
        acc[b] += wv.x * xv.x + wv.y * xv.y + wv.z * xv.z + wv.w * xv.w;
      }
    }
  }
#pragma unroll
  for (int b = 0; b < 32; ++b) {
    float v = acc[b];
    v += __shfl_xor(v, 1);
    v += __shfl_xor(v, 2);
    v += __shfl_xor(v, 4);
    acc[b] = v;
  }
  if (s == 0) {
    float bv = bias ? bias[n] : 0.f;
#pragma unroll
    for (int b = 0; b < 32; ++b) {
      float val = acc[b] + bv;
      if (n < split) out0[(size_t)b * split + n] = val;
      else out1[(size_t)b * (N - split) + (n - split)] = val;
    }
  }
}

// ---------------- proj + argmax fused ----------------
// gemvB core (K=1536, N=8000); per-block key reduce then one atomicMax per (block,b).
// key = ordered(val)<<32 | (0xFFFFFFFF - n)  -> max key == max val, ties -> smallest n.
__global__ __launch_bounds__(256) void proj_argmax_kernel(
    const float* __restrict__ A1, int len1,
    const float* __restrict__ A2, int len2,
    const float* __restrict__ W, const float* __restrict__ bias,
    unsigned long long* __restrict__ keys) {
  int tid = threadIdx.x;
  int s = tid & 7, nl = tid >> 3;
  int n = blockIdx.x * 32 + nl;
  __shared__ float4 xs4[32 * 32];
  __shared__ unsigned long long ksh[32][33];
  float acc[32];
#pragma unroll
  for (int b = 0; b < 32; ++b) acc[b] = 0.f;
  int K = len1 + len2;
  const float4* W4 = (const float4*)(W + (size_t)n * K);
  int K4 = K >> 2;
  int len1_4 = len1 >> 2;
  for (int k0 = 0; k0 < K4; k0 += 32) {
    __syncthreads();
    for (int idx = tid; idx < 1024; idx += 256) {
      int b = idx >> 5, kf = idx & 31;
      int gk = k0 + kf;
      float4 v;
      if (gk < len1_4) v = ((const float4*)(A1 + (size_t)b * len1))[gk];
      else v = ((const float4*)(A2 + (size_t)b * len2))[gk - len1_4];
      xs4[idx] = v;
    }
    __syncthreads();
    const float4* wp = W4 + k0;
#pragma unroll
    for (int j = 0; j < 4; ++j) {
      float4 wv = wp[j * 8 + s];
      const float4* xp = xs4 + j * 8 + s;
#pragma unroll
      for (int b = 0; b < 32; ++b) {
        float4 xv = xp[b * 32];
        acc[b] += wv.x * xv.x + wv.y * xv.y + wv.z * xv.z + wv.w * xv.w;
      }
    }
  }
#pragma unroll
  for (int b = 0; b < 32; ++b) {
    float v = acc[b];
    v += __shfl_xor(v, 1);
    v += __shfl_xor(v, 2);
    v += __shfl_xor(v, 4);
    acc[b] = v;
  }
  if (s == 0) {
    float bv = bias[n];
#pragma unroll
    for (int b = 0; b < 32; ++b) {
      float val = acc[b] + bv;
      unsigned u = __float_as_uint(val);
      u = (u & 0x80000000u) ? ~u : (u | 0x80000000u);
      ksh[nl][b] = ((unsigned long long)u << 32) | (unsigned long long)(0xFFFFFFFFu - (unsigned)n);
    }
  }
  __syncthreads();
  if (tid < 32) {
    unsigned long long best = 0ULL;
#pragma unroll 8
    for (int q = 0; q < 32; ++q) {
      unsigned long long v = ksh[q][tid];
      if (v > best) best = v;
    }
    atomicMax(&keys[tid], best);
  }
}

// ---------------- fused attention: prev-argmax decode + d-gemv + score + softmax + ctx ----
__global__ __launch_bounds__(512) void attn_fused(
    const float* __restrict__ h1,       // [32][512]
    const float* __restrict__ Wd,       // [512][512]
    const float* __restrict__ v,        // [512]
    const float* __restrict__ enc_proj, // [32][128][512]
    const float* __restrict__ enc_out,  // [32][128][1024]
    float* __restrict__ ctx,            // [32][1024]
    const unsigned long long* __restrict__ keys,
    int* __restrict__ tok, int* __restrict__ decoded, int step) {
  int b = blockIdx.x;
  int tid = threadIdx.x;
  if (step > 0 && b == 0 && tid < 32) {
    unsigned long long k = keys[tid];
    int n = (int)(0xFFFFFFFFu - (unsigned)(k & 0xFFFFFFFFull));
    tok[tid] = n;
    decoded[tid * 50 + step] = n;  // token produced at step-1 -> column step
  }
  __shared__ float hs[512];
  __shared__ float d[512];
  __shared__ float red[512];
  __shared__ float sc[128];
  hs[tid] = h1[b * 512 + tid];
  __syncthreads();
  {  // d[a] = Wd[a,:] . h1[b,:]
    const float* w = Wd + (size_t)tid * 512;
    float s = 0.f;
    for (int k = 0; k < 512; k += 4) {
      float4 wv = *(const float4*)&w[k];
      float4 hv = *(const float4*)&hs[k];
      s += hv.x * wv.x + hv.y * wv.y + hv.z * wv.z + hv.w * wv.w;
    }
    d[tid] = s;
  }
  __syncthreads();
  {
    int t = tid >> 2, part = tid & 3;
    const float* ep = enc_proj + ((size_t)b * 128 + t) * 512 + part * 128;
    const float* dd = d + part * 128;
    const float* vv = v + part * 128;
    float s = 0.f;
    for (int a = 0; a < 128; ++a) s += tanhf(ep[a] + dd[a]) * vv[a];
    red[tid] = s;
  }
  __syncthreads();
  if (tid < 128) sc[tid] = red[tid * 4] + red[tid * 4 + 1] + red[tid * 4 + 2] + red[tid * 4 + 3];
  __syncthreads();
  if (tid == 0) {
    float m = -1e30f;
    for (int t = 0; t < 128; ++t) m = fmaxf(m, sc[t]);
    float sum = 0.f;
    for (int t = 0; t < 128; ++t) { float e = expf(sc[t] - m); sc[t] = e; sum += e; }
    float inv = 1.f / sum;
    for (int t = 0; t < 128; ++t) sc[t] *= inv;
  }
  __syncthreads();
  for (int e = tid; e < 1024; e += 512) {
    const float* eo = enc_out + (size_t)b * 131072 + e;
    float s = 0.f;
    for (int t = 0; t < 128; ++t) s += sc[t] * eo[(size_t)t * 1024];
    ctx[b * 1024 + e] = s;
  }
}

__global__ void final_tok_kernel(const unsigned long long* __restrict__ keys,
                                 int* __restrict__ decoded) {
  int b = threadIdx.x;
  if (b >= 32) return;
  int n = (int)(0xFFFFFFFFu - (unsigned)(keys[b] & 0xFFFFFFFFull));
  decoded[b * 50 + 49] = n;
}

__global__ void init_kernel(int* __restrict__ tok, int* __restrict__ decoded) {
  int b = threadIdx.x;
  if (b >= 32) return;
  tok[b] = 1;
  decoded[b * 50] = 1;
}

__global__ void zero_kernel(float* __restrict__ p, int n) {
  int i = blockIdx.x * 256 + threadIdx.x;
  if (i < n) p[i] = 0.f;
}

extern "C" void kernel_launch(void* const* d_in, const int* in_sizes, int n_in,
                              void* d_out, int out_size, void* d_ws, size_t ws_size,
                              hipStream_t stream) {
  const float* features  = (const float*)d_in[0];
  const float* conv_w1   = (const float*)d_in[1];
  const float* conv_b1   = (const float*)d_in[2];
  const float* conv_w2   = (const float*)d_in[3];
  const float* conv_b2   = (const float*)d_in[4];
  const float* enc_Wih_f = (const float*)d_in[5];
  const float* enc_Whh_f = (const float*)d_in[6];
  const float* enc_bih_f = (const float*)d_in[7];
  const float* enc_bhh_f = (const float*)d_in[8];
  const float* enc_Wih_b = (const float*)d_in[9];
  const float* enc_Whh_b = (const float*)d_in[10];
  const float* enc_bih_b = (const float*)d_in[11];
  const float* enc_bhh_b = (const float*)d_in[12];
  const float* bridge_W  = (const float*)d_in[13];
  const float* bridge_b  = (const float*)d_in[14];
  const float* emb       = (const float*)d_in[15];
  const float* attn_We   = (const float*)d_in[16];
  const float* attn_Wd   = (const float*)d_in[17];
  const float* attn_v    = (const float*)d_in[18];
  const float* dec_Wih0  = (const float*)d_in[19];
  const float* dec_Whh0  = (const float*)d_in[20];
  const float* dec_bih0  = (const float*)d_in[21];
  const float* dec_bhh0  = (const float*)d_in[22];
  const float* dec_Wih1  = (const float*)d_in[23];
  const float* dec_Whh1  = (const float*)d_in[24];
  const float* dec_bih1  = (const float*)d_in[25];
  const float* dec_bhh1  = (const float*)d_in[26];
  const float* proj_W    = (const float*)d_in[27];
  const float* proj_b    = (const float*)d_in[28];
  int* decoded = (int*)d_out;

  // ---- static workspace ----
  float* ws = nullptr;
  hipGetSymbolAddress((void**)&ws, HIP_SYMBOL(g_ws));
  float* P       = ws;                    // 10,485,760
  float* y1      = ws + 10485760;         //  4,194,304
  float* x2      = ws + 14680064;         //  2,097,152
  float* gi_f    = ws + 16777216;         //  6,291,456
  float* gi_b    = ws + 23068672;         //  6,291,456
  float* enc_out = ws + 29360128;         //  4,194,304
  float* enc_pj  = ws + 33554432;         //  2,097,152
  float* h_enc   = ws + 35651584;         //     65,536 (2 bufs x 2 dir x 32 x 512)
  float* h0d     = ws + 35717120;         //     32,768
  float* h1d     = ws + 35749888;         //     32,768
  float* ctxb    = ws + 35782656;         //     32,768
  unsigned long long* keys = (unsigned long long*)(ws + 35815424);  // 32 u64
  int*   tok     = (int*)(ws + 35815488); //         32

  // ---- conv front-end as im2col + GEMM (+bias+relu) ----
  im2col1_kernel<<<40960, 256, 0, stream>>>(features, P);
  sgemm128<<<dim3(4, 64), 256, 0, stream>>>(P, conv_w1, conv_b1, y1, 8192, 512, 1280, 1);
  im2col2_kernel<<<40960, 256, 0, stream>>>(y1, P);
  sgemm128<<<dim3(4, 32), 256, 0, stream>>>(P, conv_w2, conv_b2, x2, 4096, 512, 2560, 1);

  // ---- GRU input transforms ----
  sgemm128<<<dim3(12, 32), 256, 0, stream>>>(x2, enc_Wih_f, enc_bih_f, gi_f, 4096, 1536, 512, 0);
  sgemm128<<<dim3(12, 32), 256, 0, stream>>>(x2, enc_Wih_b, enc_bih_b, gi_b, 4096, 1536, 512, 0);

  // ---- bidirectional encoder recurrence ----
  zero_kernel<<<256, 256, 0, stream>>>(h_enc, 65536);
  for (int s = 0; s < 128; ++s) {
    enc_gru_step<<<256, 128, 0, stream>>>(gi_f, gi_b,
        enc_Whh_f, enc_bhh_f, enc_Whh_b, enc_bhh_b,
        h_enc + (s & 1) * 32768, h_enc + ((s + 1) & 1) * 32768, enc_out, s);
  }
  float* h_fin = h_enc;  // final state in buffer 0 after 128 steps

  // ---- bridge ----
  gemvB<<<32, 256, 0, stream>>>(h_fin, nullptr, 512, h_fin + 16384, 512,
      bridge_W, bridge_b, h0d, h1d, 512, 1024, 1024);

  // ---- enc_proj ----
  sgemm128<<<dim3(4, 32), 256, 0, stream>>>(enc_out, attn_We, nullptr, enc_pj, 4096, 512, 1024, 0);

  init_kernel<<<1, 64, 0, stream>>>(tok, decoded);

  // ---- greedy attention decoder, 49 steps x 4 kernels ----
  for (int s = 0; s < 49; ++s) {
    int cur = s & 1, nxt = (s + 1) & 1;
    attn_fused<<<32, 512, 0, stream>>>(h1d + cur * 16384, attn_Wd, attn_v,
                                       enc_pj, enc_out, ctxb, keys, tok, decoded, s);
    dec_gru_fused<<<64, 256, 0, stream>>>(emb, tok, 512, ctxb, 1024,
        dec_Wih0, dec_bih0, dec_Whh0, dec_bhh0,
        h0d + cur * 16384, h0d + nxt * 16384, nullptr);
    dec_gru_fused<<<64, 256, 0, stream>>>(h0d + nxt * 16384, nullptr, 512, nullptr, 0,
        dec_Wih1, dec_bih1, dec_Whh1, dec_bhh1,
        h1d + cur * 16384, h1d + nxt * 16384, keys);
    proj_argmax_kernel<<<250, 256, 0, stream>>>(h1d + nxt * 16384, 512, ctxb, 1024,
        proj_W, proj_b, keys);
  }
  final_tok_kernel<<<1, 32, 0, stream>>>(keys, decoded);
}